// Round 10
// baseline (299.366 us; speedup 1.0000x reference)
//
#include <hip/hip_runtime.h>

#define BB 64
#define PP 8732
#define NOBJ 16
#define NC 81
#define THRESH 0.5f
#define NEGPOS 3
#define NCHUNK 16
#define CHUNK ((PP + NCHUNK - 1) / NCHUNK)   // 546; 16*546=8736, last chunk 542
#define NBLK 2183             // fused-conf blocks: 2183*256 == BB*PP

#define TK_THREADS 1024
#define TK_KEYS 9             // 9*1024 = 9216 >= 8732
#define TK_WAVES (TK_THREADS / 64)           // 16

__device__ __forceinline__ float smooth_l1(float x) {
    float ax = fabsf(x);
    return (ax < 1.0f) ? 0.5f * x * x : ax - 0.5f;
}

// ---------- Kernel 1: per-truth best prior, per-chunk partials ----------
// NCHUNK=16 -> 1024 blocks (4/CU), ~2.1 serial iters: shallower latency-
// exposed depth. Plain stores only (R6's atomic-burst regression mechanism
// is absent). One block zeroes the cross-dispatch scalars (stream-ordered).
__global__ __launch_bounds__(256) void k_matchA(
    const float* __restrict__ priors, const float* __restrict__ targets,
    unsigned long long* __restrict__ g_best_part,
    double* __restrict__ accum, int* __restrict__ nsum,
    int* __restrict__ done_cnt)
{
    const int chunk = blockIdx.x;
    const int b = blockIdx.y;
    const int tid = threadIdx.x;

    __shared__ float s_tx1[NOBJ], s_ty1[NOBJ], s_tx2[NOBJ], s_ty2[NOBJ];
    __shared__ float s_area[NOBJ];
    __shared__ unsigned long long s_best[NOBJ];

    if (tid < NOBJ) {
        const float* t = targets + ((size_t)b * NOBJ + tid) * 5;
        float x1 = t[0], y1 = t[1], x2 = t[2], y2 = t[3];
        s_tx1[tid] = x1; s_ty1[tid] = y1; s_tx2[tid] = x2; s_ty2[tid] = y2;
        s_area[tid] = (x2 - x1) * (y2 - y1);
        s_best[tid] = 0ull;
    }
    if (chunk == 0 && b == 0 && tid == 0) {
        accum[0] = 0.0; nsum[0] = 0; done_cnt[0] = 0;
    }
    __syncthreads();

    unsigned long long best[NOBJ];
    #pragma unroll
    for (int t = 0; t < NOBJ; ++t) best[t] = 0ull;

    const int p0 = chunk * CHUNK;
    int p1 = p0 + CHUNK; if (p1 > PP) p1 = PP;
    for (int p = p0 + tid; p < p1; p += 256) {
        float4 pr = ((const float4*)priors)[p];
        float px1 = pr.x - pr.z * 0.5f, py1 = pr.y - pr.w * 0.5f;
        float px2 = pr.x + pr.z * 0.5f, py2 = pr.y + pr.w * 0.5f;
        float pa = (px2 - px1) * (py2 - py1);
        unsigned revp = 0xFFFFFFFFu - (unsigned)p;   // tie -> smaller p wins
        #pragma unroll
        for (int t = 0; t < NOBJ; ++t) {
            float ix1 = fmaxf(s_tx1[t], px1), iy1 = fmaxf(s_ty1[t], py1);
            float ix2 = fminf(s_tx2[t], px2), iy2 = fminf(s_ty2[t], py2);
            float iw = fmaxf(ix2 - ix1, 0.f), ih = fmaxf(iy2 - iy1, 0.f);
            float inter = iw * ih;
            float iou = inter / (s_area[t] + pa - inter);
            unsigned long long key =
                ((unsigned long long)__float_as_uint(iou) << 32) | revp;
            if (key > best[t]) best[t] = key;
        }
    }
    #pragma unroll
    for (int t = 0; t < NOBJ; ++t) {
        unsigned long long v = best[t];
        for (int o = 32; o > 0; o >>= 1) {
            unsigned long long w = __shfl_down(v, o);
            if (w > v) v = w;
        }
        if ((tid & 63) == 0) atomicMax(&s_best[t], v);
    }
    __syncthreads();
    if (tid < NOBJ)
        g_best_part[((size_t)b * NOBJ + tid) * NCHUNK + chunk] = s_best[tid];
}

// ---------- Kernel 2: fused per-prior match + conf loss ----------
// (byte-identical to the R7/R9-verified kernel except NCHUNK merge width)
__global__ __launch_bounds__(256) void k_conf_fused(
    const float* __restrict__ loc_data, const float* __restrict__ conf_data,
    const float* __restrict__ priors, const float* __restrict__ targets,
    const unsigned long long* __restrict__ g_best_part,
    float* __restrict__ lcm, float* __restrict__ llp_part,
    int2* __restrict__ np_part)
{
    __shared__ float4 s_buf4[2][648];        // 2 x 32 rows x 81 floats
    __shared__ float s_tx1[2][NOBJ], s_ty1[2][NOBJ];
    __shared__ float s_tx2[2][NOBJ], s_ty2[2][NOBJ];
    __shared__ float s_lab[2][NOBJ], s_area[2][NOBJ];
    __shared__ int s_bpi[2][NOBJ];
    __shared__ int s_conf[256];
    const int tid = threadIdx.x;
    const int base_row = blockIdx.x * 256;
    const int b0 = base_row / PP;
    int split = (b0 + 1) * PP - base_row;    // rows of batch b0 in this block
    if (split > 256) split = 256;
    const bool two = (split < 256);          // block spans two batches

    // truths + best-prior-idx for (up to) two batches
    if (tid < 32) {
        int bt = tid >> 4, t = tid & 15;
        if (bt == 0 || two) {
            int gb = b0 + bt;
            const float* tp = targets + ((size_t)gb * NOBJ + t) * 5;
            float x1 = tp[0], y1 = tp[1], x2 = tp[2], y2 = tp[3];
            s_tx1[bt][t] = x1; s_ty1[bt][t] = y1;
            s_tx2[bt][t] = x2; s_ty2[bt][t] = y2;
            s_lab[bt][t] = tp[4];
            s_area[bt][t] = (x2 - x1) * (y2 - y1);
            const unsigned long long* part =
                g_best_part + ((size_t)gb * NOBJ + t) * NCHUNK;
            unsigned long long m = part[0];
            #pragma unroll
            for (int c = 1; c < NCHUNK; ++c)
                if (part[c] > m) m = part[c];
            s_bpi[bt][t] = (int)(0xFFFFFFFFu - (unsigned)(m & 0xFFFFFFFFull));
        }
    }

    // issue initial conf loads (latency hides under the match phase)
    const float4* g4base = (const float4*)conf_data;
    float4 t0, t1, t2;
    {
        const float4* g4 = g4base + (size_t)base_row * NC / 4;
        t0 = g4[tid]; t1 = g4[tid + 256];
        if (tid < 136) t2 = g4[tid + 512];
    }
    __syncthreads();

    // ---- match phase: one row per thread, full wave utilization ----
    const int seg = (tid < split) ? 0 : 1;
    const int row = base_row + tid;
    const int p = row - (b0 + seg) * PP;
    float llp = 0.f;
    int np0 = 0, np1 = 0;
    {
        float4 pr = ((const float4*)priors)[p];
        float px1 = pr.x - pr.z * 0.5f, py1 = pr.y - pr.w * 0.5f;
        float px2 = pr.x + pr.z * 0.5f, py2 = pr.y + pr.w * 0.5f;
        float pa = (px2 - px1) * (py2 - py1);
        float bt_ov = -1.f;
        int bt_idx = 0;
        #pragma unroll
        for (int t = 0; t < NOBJ; ++t) {
            float ix1 = fmaxf(s_tx1[seg][t], px1), iy1 = fmaxf(s_ty1[seg][t], py1);
            float ix2 = fminf(s_tx2[seg][t], px2), iy2 = fminf(s_ty2[seg][t], py2);
            float iw = fmaxf(ix2 - ix1, 0.f), ih = fmaxf(iy2 - iy1, 0.f);
            float inter = iw * ih;
            float iou = inter / (s_area[seg][t] + pa - inter);
            if (iou > bt_ov) { bt_ov = iou; bt_idx = t; }  // strict >: first-max
        }
        #pragma unroll
        for (int i = 0; i < NOBJ; ++i)           // last-wins scatter override
            if (s_bpi[seg][i] == p) { bt_idx = i; bt_ov = 2.0f; }

        int c = (bt_ov < THRESH) ? 0 : ((int)s_lab[seg][bt_idx] + 1);
        s_conf[tid] = c;

        if (c > 0) {
            if (seg == 0) np0 = 1; else np1 = 1;
            float mx1 = s_tx1[seg][bt_idx], my1 = s_ty1[seg][bt_idx];
            float mx2 = s_tx2[seg][bt_idx], my2 = s_ty2[seg][bt_idx];
            float gcx = ((mx1 + mx2) * 0.5f - pr.x) / (0.1f * pr.z);
            float gcy = ((my1 + my2) * 0.5f - pr.y) / (0.1f * pr.w);
            float gw = logf((mx2 - mx1) / pr.z) / 0.2f;
            float gh = logf((my2 - my1) / pr.w) / 0.2f;
            float4 ld = ((const float4*)loc_data)[row];
            llp += smooth_l1(ld.x - gcx) + smooth_l1(ld.y - gcy) +
                   smooth_l1(ld.z - gw) + smooth_l1(ld.w - gh);
        }
    }
    __syncthreads();                         // s_conf ready

    // ---- conf phase: verified double-buffered loop ----
    const int r = tid >> 3;                  // row in half-chunk (0..31)
    const int s = tid & 7;                   // octet segment (0..7)
    const int seg_start = s * 10;
    const int seg_len = (s == 7) ? 11 : 10;  // 7*10 + 11 = 81

    for (int h = 0; h < 8; ++h) {
        float4* buf = s_buf4[h & 1];
        buf[tid] = t0; buf[tid + 256] = t1;
        if (tid < 136) buf[tid + 512] = t2;
        if (h + 1 < 8) {                     // issue next loads (latency hidden)
            const float4* g4 = g4base + (size_t)(base_row + (h + 1) * 32) * NC / 4;
            t0 = g4[tid]; t1 = g4[tid + 256];
            if (tid < 136) t2 = g4[tid + 512];
        }
        __syncthreads();                     // single barrier per half-chunk

        const float* myrow = (const float*)buf + r * NC;
        float v[11];
        #pragma unroll
        for (int j = 0; j < 11; ++j) v[j] = myrow[seg_start + j];

        float m = -1e30f;
        #pragma unroll
        for (int j = 0; j < 11; ++j) m = fmaxf(m, (j < seg_len) ? v[j] : -1e30f);
        m = fmaxf(m, __shfl_xor(m, 1));
        m = fmaxf(m, __shfl_xor(m, 2));
        m = fmaxf(m, __shfl_xor(m, 4));
        float e = 0.f;
        #pragma unroll
        for (int j = 0; j < 11; ++j) e += (j < seg_len) ? __expf(v[j] - m) : 0.f;
        e += __shfl_xor(e, 1);
        e += __shfl_xor(e, 2);
        e += __shfl_xor(e, 4);

        if (s == 0) {
            int idx = h * 32 + r;
            int c = s_conf[idx];
            float lse = m + __logf(e);
            float lc = lse - myrow[c];
            bool pos = c > 0;
            lcm[base_row + idx] = pos ? 0.f : lc;
            if (pos) llp += lc;              // positive conf loss joins loc loss
        }
    }

    // ---- block reduce: llp (float), np0, np1 -> plain-store partials ----
    for (int o = 32; o > 0; o >>= 1) {
        llp += __shfl_down(llp, o);
        np0 += __shfl_down(np0, o);
        np1 += __shfl_down(np1, o);
    }
    __shared__ float s_l[4];
    __shared__ int s_n0[4], s_n1[4];
    if ((tid & 63) == 0) {
        s_l[tid >> 6] = llp; s_n0[tid >> 6] = np0; s_n1[tid >> 6] = np1;
    }
    __syncthreads();
    if (tid == 0) {
        llp_part[blockIdx.x] = s_l[0] + s_l[1] + s_l[2] + s_l[3];
        np_part[blockIdx.x] = make_int2(s_n0[0] + s_n0[1] + s_n0[2] + s_n0[3],
                                        s_n1[0] + s_n1[1] + s_n1[2] + s_n1[3]);
    }
}

// ---------- Kernel 3: per-batch top-k via radix-256 select + finalize ----------
// Latency fix: 1024 threads (16 waves, 4/SIMD) -- topk is latency-bound
// (19us measured vs ~5us of work at 512 thr): halves per-thread serial key
// work and round-0 per-wave same-bin contention, doubles waves available to
// hide the 16-barrier chain. Per-wave private histograms (16 x 256).
__global__ __launch_bounds__(TK_THREADS) void k_topk(
    const float* __restrict__ lcm, const int2* __restrict__ np_part,
    const float* __restrict__ llp_part,
    double* __restrict__ accum, int* __restrict__ nsum,
    int* __restrict__ done_cnt, float* __restrict__ out)
{
    const int b = blockIdx.x, tid = threadIdx.x;
    const int wv = tid >> 6;                 // wave id (0..15)

    // ---- np_b from block segment partials (<=36 covering blocks) ----
    __shared__ int s_npb;
    {
        int gs = (b * PP) >> 8;
        int ge = ((b + 1) * PP - 1) >> 8;
        int cnt = ge - gs + 1;               // <= 36 < 64
        int mynp = 0;
        if (tid < cnt) {
            int g = gs + tid;
            int2 e = np_part[g];
            int bg0 = (g << 8) / PP;
            mynp = (bg0 == b) ? e.x : e.y;   // segment belonging to batch b
        }
        if (tid < 64) {
            for (int o = 32; o > 0; o >>= 1) mynp += __shfl_down(mynp, o);
            if (tid == 0) s_npb = mynp;
        }
    }

    unsigned key[TK_KEYS];
    #pragma unroll
    for (int j = 0; j < TK_KEYS; ++j) {
        int i = tid + j * TK_THREADS;
        key[j] = (i < PP) ? __float_as_uint(lcm[(size_t)b * PP + i]) : 0u;
    }
    __shared__ int s_hist[TK_WAVES][256];    // per-wave private histograms
    __shared__ int s_vk[2];                  // {selected byte, next kk}
    __syncthreads();
    const int np = s_npb;
    int k = NEGPOS * np;
    if (k > PP - 1) k = PP - 1;

    unsigned P = 0;
    int kk = k;
    #pragma unroll
    for (int rd = 0; rd < 4; ++rd) {
        const int shift = 24 - 8 * rd;
        for (int i = tid; i < TK_WAVES * 256; i += TK_THREADS)
            ((int*)s_hist)[i] = 0;
        __syncthreads();
        const unsigned hi_mask = (rd == 0) ? 0u : (0xFFFFFFFFu << (shift + 8));
        #pragma unroll
        for (int j = 0; j < TK_KEYS; ++j) {
            int i = tid + j * TK_THREADS;
            if (i < PP && (((key[j] ^ P) & hi_mask) == 0u))
                atomicAdd(&s_hist[wv][(key[j] >> shift) & 255], 1);
        }
        __syncthreads();
        if (tid < 64) {                      // wave 0: reduce 16 copies + scan
            int h0 = 0, h1 = 0, h2 = 0, h3 = 0;
            #pragma unroll
            for (int w = 0; w < TK_WAVES; ++w) {
                h0 += s_hist[w][4 * tid + 0];
                h1 += s_hist[w][4 * tid + 1];
                h2 += s_hist[w][4 * tid + 2];
                h3 += s_hist[w][4 * tid + 3];
            }
            int s3 = h3, s2 = h2 + s3, s1 = h1 + s2, s0 = h0 + s1;
            int acc = s0;
            #pragma unroll
            for (int o = 1; o < 64; o <<= 1) {
                int t = __shfl_down(acc, o);
                if (tid + o < 64) acc += t;  // inclusive suffix over lane totals
            }
            int excl = acc - s0;
            int c0 = s0 + excl, c1 = s1 + excl, c2 = s2 + excl, c3 = s3 + excl;
            unsigned long long m = __ballot(c0 >= kk);
            int L = 63 - __clzll(m);         // highest lane containing the pivot
            if (tid == L) {
                int vi, cnext;
                if (c3 >= kk)      { vi = 3; cnext = excl; }
                else if (c2 >= kk) { vi = 2; cnext = c3; }
                else if (c1 >= kk) { vi = 1; cnext = c2; }
                else               { vi = 0; cnext = c1; }
                s_vk[0] = 4 * tid + vi;
                s_vk[1] = kk - cnext;
            }
        }
        __syncthreads();
        P |= ((unsigned)s_vk[0]) << shift;
        kk = s_vk[1];
        __syncthreads();                     // s_hist reused next round
    }

    const unsigned T = P;
    float sum = 0.f;
    int cgt = 0;
    #pragma unroll
    for (int j = 0; j < TK_KEYS; ++j) {
        if (key[j] > T) { sum += __uint_as_float(key[j]); cgt++; }
    }
    for (int o = 32; o > 0; o >>= 1) {
        sum += __shfl_down(sum, o);
        cgt += __shfl_down(cgt, o);
    }
    __shared__ float s_s[TK_WAVES];
    __shared__ int s_c[TK_WAVES];
    __shared__ int s_last;
    if ((tid & 63) == 0) { s_s[wv] = sum; s_c[wv] = cgt; }
    __syncthreads();
    if (tid == 0) {
        float tot = 0.f; int ctot = 0;
        for (int w = 0; w < TK_WAVES; ++w) { tot += s_s[w]; ctot += s_c[w]; }
        float neg = tot + (float)(k - ctot) * __uint_as_float(T);
        atomicAdd(&accum[0], (double)neg);
        atomicAdd(nsum, np);
        __threadfence();
        s_last = (atomicAdd(done_cnt, 1) == BB - 1) ? 1 : 0;
    }
    __syncthreads();

    if (s_last) {                            // last block: finalize
        double acc = 0.0;
        for (int i = tid; i < NBLK; i += TK_THREADS)
            acc += (double)llp_part[i];      // cross-dispatch data: plain OK
        for (int o = 32; o > 0; o >>= 1) acc += __shfl_down(acc, o);
        __shared__ double s_d[TK_WAVES];
        if ((tid & 63) == 0) s_d[wv] = acc;
        __syncthreads();
        if (tid == 0) {
            double llp_tot = 0.0;
            for (int w = 0; w < TK_WAVES; ++w) llp_tot += s_d[w];
            double neg_tot = atomicAdd(&accum[0], 0.0);
            int N = atomicAdd(nsum, 0);
            out[0] = (float)((llp_tot + neg_tot) / (double)N);   // ALPHA = 1
        }
    }
}

extern "C" void kernel_launch(void* const* d_in, const int* in_sizes, int n_in,
                              void* d_out, int out_size, void* d_ws, size_t ws_size,
                              hipStream_t stream) {
    const float* loc_data  = (const float*)d_in[0];
    const float* conf_data = (const float*)d_in[1];
    const float* priors    = (const float*)d_in[2];
    const float* targets   = (const float*)d_in[3];

    char* ws = (char*)d_ws;
    // layout: [0,8) double accum[1]; [8,12) int nsum; [12,16) int done_cnt;
    //         [512, 512+64*16*16*8=131584) u64 g_best_part[b][t][chunk];
    //         [131584, +NBLK*4) float llp_part;
    //         [140320, +NBLK*8) int2 np_part;
    //         [157792, +BB*PP*4) float lcm
    double* accum = (double*)ws;
    int* nsum = (int*)(ws + 8);
    int* done_cnt = (int*)(ws + 12);
    unsigned long long* g_best_part = (unsigned long long*)(ws + 512);
    float* llp_part = (float*)(ws + 131584);
    int2* np_part = (int2*)(ws + 140320);
    float* lcm = (float*)(ws + 157792);

    // no memset dispatch: all partials plain-stored and fully overwritten;
    // accum/nsum/done_cnt zeroed inside k_matchA (stream-ordered).

    dim3 mg(NCHUNK, BB);
    k_matchA<<<mg, 256, 0, stream>>>(priors, targets, g_best_part,
                                     accum, nsum, done_cnt);

    k_conf_fused<<<NBLK, 256, 0, stream>>>(loc_data, conf_data, priors, targets,
                                           g_best_part, lcm, llp_part, np_part);

    k_topk<<<BB, TK_THREADS, 0, stream>>>(lcm, np_part, llp_part,
                                          accum, nsum, done_cnt, (float*)d_out);
}

// Round 11
// 294.179 us; speedup vs baseline: 1.0176x; 1.0176x over previous
//
#include <hip/hip_runtime.h>

#define BB 64
#define PP 8732
#define NOBJ 16
#define NC 81
#define THRESH 0.5f
#define NEGPOS 3
#define NCHUNK 8
#define CHUNK ((PP + NCHUNK - 1) / NCHUNK)   // 1092; last chunk = 1088
#define NBLK 2183             // fused-conf blocks: 2183*256 == BB*PP

#define TK_THREADS 512
#define TK_KEYS 18            // 17*512 = 8704; threads 0..27 hold an 18th key

__device__ __forceinline__ float smooth_l1(float x) {
    float ax = fabsf(x);
    return (ax < 1.0f) ? 0.5f * x * x : ax - 0.5f;
}

// ---------- Kernel 1: per-truth best prior, per-chunk partials ----------
// (R9-verified best config: 512 blocks, ~4.3 serial iters, plain stores.)
__global__ __launch_bounds__(256) void k_matchA(
    const float* __restrict__ priors, const float* __restrict__ targets,
    unsigned long long* __restrict__ g_best_part,
    double* __restrict__ accum, int* __restrict__ nsum,
    int* __restrict__ done_cnt)
{
    const int chunk = blockIdx.x;
    const int b = blockIdx.y;
    const int tid = threadIdx.x;

    __shared__ float s_tx1[NOBJ], s_ty1[NOBJ], s_tx2[NOBJ], s_ty2[NOBJ];
    __shared__ float s_area[NOBJ];
    __shared__ unsigned long long s_best[NOBJ];

    if (tid < NOBJ) {
        const float* t = targets + ((size_t)b * NOBJ + tid) * 5;
        float x1 = t[0], y1 = t[1], x2 = t[2], y2 = t[3];
        s_tx1[tid] = x1; s_ty1[tid] = y1; s_tx2[tid] = x2; s_ty2[tid] = y2;
        s_area[tid] = (x2 - x1) * (y2 - y1);
        s_best[tid] = 0ull;
    }
    if (chunk == 0 && b == 0 && tid == 0) {
        accum[0] = 0.0; nsum[0] = 0; done_cnt[0] = 0;
    }
    __syncthreads();

    unsigned long long best[NOBJ];
    #pragma unroll
    for (int t = 0; t < NOBJ; ++t) best[t] = 0ull;

    const int p0 = chunk * CHUNK;
    int p1 = p0 + CHUNK; if (p1 > PP) p1 = PP;
    for (int p = p0 + tid; p < p1; p += 256) {
        float4 pr = ((const float4*)priors)[p];
        float px1 = pr.x - pr.z * 0.5f, py1 = pr.y - pr.w * 0.5f;
        float px2 = pr.x + pr.z * 0.5f, py2 = pr.y + pr.w * 0.5f;
        float pa = (px2 - px1) * (py2 - py1);
        unsigned revp = 0xFFFFFFFFu - (unsigned)p;   // tie -> smaller p wins
        #pragma unroll
        for (int t = 0; t < NOBJ; ++t) {
            float ix1 = fmaxf(s_tx1[t], px1), iy1 = fmaxf(s_ty1[t], py1);
            float ix2 = fminf(s_tx2[t], px2), iy2 = fminf(s_ty2[t], py2);
            float iw = fmaxf(ix2 - ix1, 0.f), ih = fmaxf(iy2 - iy1, 0.f);
            float inter = iw * ih;
            float iou = inter / (s_area[t] + pa - inter);
            unsigned long long key =
                ((unsigned long long)__float_as_uint(iou) << 32) | revp;
            if (key > best[t]) best[t] = key;
        }
    }
    #pragma unroll
    for (int t = 0; t < NOBJ; ++t) {
        unsigned long long v = best[t];
        for (int o = 32; o > 0; o >>= 1) {
            unsigned long long w = __shfl_down(v, o);
            if (w > v) v = w;
        }
        if ((tid & 63) == 0) atomicMax(&s_best[t], v);
    }
    __syncthreads();
    if (tid < NOBJ)
        g_best_part[((size_t)b * NOBJ + tid) * NCHUNK + chunk] = s_best[tid];
}

// ---------- Kernel 2: fused per-prior match + conf loss ----------
// (byte-identical to the R7/R9-verified kernel)
__global__ __launch_bounds__(256) void k_conf_fused(
    const float* __restrict__ loc_data, const float* __restrict__ conf_data,
    const float* __restrict__ priors, const float* __restrict__ targets,
    const unsigned long long* __restrict__ g_best_part,
    float* __restrict__ lcm, float* __restrict__ llp_part,
    int2* __restrict__ np_part)
{
    __shared__ float4 s_buf4[2][648];        // 2 x 32 rows x 81 floats
    __shared__ float s_tx1[2][NOBJ], s_ty1[2][NOBJ];
    __shared__ float s_tx2[2][NOBJ], s_ty2[2][NOBJ];
    __shared__ float s_lab[2][NOBJ], s_area[2][NOBJ];
    __shared__ int s_bpi[2][NOBJ];
    __shared__ int s_conf[256];
    const int tid = threadIdx.x;
    const int base_row = blockIdx.x * 256;
    const int b0 = base_row / PP;
    int split = (b0 + 1) * PP - base_row;    // rows of batch b0 in this block
    if (split > 256) split = 256;
    const bool two = (split < 256);          // block spans two batches

    // truths + best-prior-idx for (up to) two batches
    if (tid < 32) {
        int bt = tid >> 4, t = tid & 15;
        if (bt == 0 || two) {
            int gb = b0 + bt;
            const float* tp = targets + ((size_t)gb * NOBJ + t) * 5;
            float x1 = tp[0], y1 = tp[1], x2 = tp[2], y2 = tp[3];
            s_tx1[bt][t] = x1; s_ty1[bt][t] = y1;
            s_tx2[bt][t] = x2; s_ty2[bt][t] = y2;
            s_lab[bt][t] = tp[4];
            s_area[bt][t] = (x2 - x1) * (y2 - y1);
            const unsigned long long* part =
                g_best_part + ((size_t)gb * NOBJ + t) * NCHUNK;
            unsigned long long m = part[0];
            #pragma unroll
            for (int c = 1; c < NCHUNK; ++c)
                if (part[c] > m) m = part[c];
            s_bpi[bt][t] = (int)(0xFFFFFFFFu - (unsigned)(m & 0xFFFFFFFFull));
        }
    }

    // issue initial conf loads (latency hides under the match phase)
    const float4* g4base = (const float4*)conf_data;
    float4 t0, t1, t2;
    {
        const float4* g4 = g4base + (size_t)base_row * NC / 4;
        t0 = g4[tid]; t1 = g4[tid + 256];
        if (tid < 136) t2 = g4[tid + 512];
    }
    __syncthreads();

    // ---- match phase: one row per thread, full wave utilization ----
    const int seg = (tid < split) ? 0 : 1;
    const int row = base_row + tid;
    const int p = row - (b0 + seg) * PP;
    float llp = 0.f;
    int np0 = 0, np1 = 0;
    {
        float4 pr = ((const float4*)priors)[p];
        float px1 = pr.x - pr.z * 0.5f, py1 = pr.y - pr.w * 0.5f;
        float px2 = pr.x + pr.z * 0.5f, py2 = pr.y + pr.w * 0.5f;
        float pa = (px2 - px1) * (py2 - py1);
        float bt_ov = -1.f;
        int bt_idx = 0;
        #pragma unroll
        for (int t = 0; t < NOBJ; ++t) {
            float ix1 = fmaxf(s_tx1[seg][t], px1), iy1 = fmaxf(s_ty1[seg][t], py1);
            float ix2 = fminf(s_tx2[seg][t], px2), iy2 = fminf(s_ty2[seg][t], py2);
            float iw = fmaxf(ix2 - ix1, 0.f), ih = fmaxf(iy2 - iy1, 0.f);
            float inter = iw * ih;
            float iou = inter / (s_area[seg][t] + pa - inter);
            if (iou > bt_ov) { bt_ov = iou; bt_idx = t; }  // strict >: first-max
        }
        #pragma unroll
        for (int i = 0; i < NOBJ; ++i)           // last-wins scatter override
            if (s_bpi[seg][i] == p) { bt_idx = i; bt_ov = 2.0f; }

        int c = (bt_ov < THRESH) ? 0 : ((int)s_lab[seg][bt_idx] + 1);
        s_conf[tid] = c;

        if (c > 0) {
            if (seg == 0) np0 = 1; else np1 = 1;
            float mx1 = s_tx1[seg][bt_idx], my1 = s_ty1[seg][bt_idx];
            float mx2 = s_tx2[seg][bt_idx], my2 = s_ty2[seg][bt_idx];
            float gcx = ((mx1 + mx2) * 0.5f - pr.x) / (0.1f * pr.z);
            float gcy = ((my1 + my2) * 0.5f - pr.y) / (0.1f * pr.w);
            float gw = logf((mx2 - mx1) / pr.z) / 0.2f;
            float gh = logf((my2 - my1) / pr.w) / 0.2f;
            float4 ld = ((const float4*)loc_data)[row];
            llp += smooth_l1(ld.x - gcx) + smooth_l1(ld.y - gcy) +
                   smooth_l1(ld.z - gw) + smooth_l1(ld.w - gh);
        }
    }
    __syncthreads();                         // s_conf ready

    // ---- conf phase: verified double-buffered loop ----
    const int r = tid >> 3;                  // row in half-chunk (0..31)
    const int s = tid & 7;                   // octet segment (0..7)
    const int seg_start = s * 10;
    const int seg_len = (s == 7) ? 11 : 10;  // 7*10 + 11 = 81

    for (int h = 0; h < 8; ++h) {
        float4* buf = s_buf4[h & 1];
        buf[tid] = t0; buf[tid + 256] = t1;
        if (tid < 136) buf[tid + 512] = t2;
        if (h + 1 < 8) {                     // issue next loads (latency hidden)
            const float4* g4 = g4base + (size_t)(base_row + (h + 1) * 32) * NC / 4;
            t0 = g4[tid]; t1 = g4[tid + 256];
            if (tid < 136) t2 = g4[tid + 512];
        }
        __syncthreads();                     // single barrier per half-chunk

        const float* myrow = (const float*)buf + r * NC;
        float v[11];
        #pragma unroll
        for (int j = 0; j < 11; ++j) v[j] = myrow[seg_start + j];

        float m = -1e30f;
        #pragma unroll
        for (int j = 0; j < 11; ++j) m = fmaxf(m, (j < seg_len) ? v[j] : -1e30f);
        m = fmaxf(m, __shfl_xor(m, 1));
        m = fmaxf(m, __shfl_xor(m, 2));
        m = fmaxf(m, __shfl_xor(m, 4));
        float e = 0.f;
        #pragma unroll
        for (int j = 0; j < 11; ++j) e += (j < seg_len) ? __expf(v[j] - m) : 0.f;
        e += __shfl_xor(e, 1);
        e += __shfl_xor(e, 2);
        e += __shfl_xor(e, 4);

        if (s == 0) {
            int idx = h * 32 + r;
            int c = s_conf[idx];
            float lse = m + __logf(e);
            float lc = lse - myrow[c];
            bool pos = c > 0;
            lcm[base_row + idx] = pos ? 0.f : lc;
            if (pos) llp += lc;              // positive conf loss joins loc loss
        }
    }

    // ---- block reduce: llp (float), np0, np1 -> plain-store partials ----
    for (int o = 32; o > 0; o >>= 1) {
        llp += __shfl_down(llp, o);
        np0 += __shfl_down(np0, o);
        np1 += __shfl_down(np1, o);
    }
    __shared__ float s_l[4];
    __shared__ int s_n0[4], s_n1[4];
    if ((tid & 63) == 0) {
        s_l[tid >> 6] = llp; s_n0[tid >> 6] = np0; s_n1[tid >> 6] = np1;
    }
    __syncthreads();
    if (tid == 0) {
        llp_part[blockIdx.x] = s_l[0] + s_l[1] + s_l[2] + s_l[3];
        np_part[blockIdx.x] = make_int2(s_n0[0] + s_n0[1] + s_n0[2] + s_n0[3],
                                        s_n1[0] + s_n1[1] + s_n1[2] + s_n1[3]);
    }
}

// ---------- Kernel 3: per-batch top-k via radix-256 select + finalize ----------
// (R9-verified: 512 threads, per-wave private histograms 8 x 256.)
__global__ __launch_bounds__(TK_THREADS) void k_topk(
    const float* __restrict__ lcm, const int2* __restrict__ np_part,
    const float* __restrict__ llp_part,
    double* __restrict__ accum, int* __restrict__ nsum,
    int* __restrict__ done_cnt, float* __restrict__ out)
{
    const int b = blockIdx.x, tid = threadIdx.x;
    const int wv = tid >> 6;                 // wave id (0..7)

    // ---- np_b from block segment partials (<=36 covering blocks) ----
    __shared__ int s_npb;
    {
        int gs = (b * PP) >> 8;
        int ge = ((b + 1) * PP - 1) >> 8;
        int cnt = ge - gs + 1;
        int mynp = 0;
        if (tid < cnt) {
            int g = gs + tid;
            int2 e = np_part[g];
            int bg0 = (g << 8) / PP;
            mynp = (bg0 == b) ? e.x : e.y;   // segment belonging to batch b
        }
        if (tid < 64) {
            for (int o = 32; o > 0; o >>= 1) mynp += __shfl_down(mynp, o);
            if (tid == 0) s_npb = mynp;
        }
    }

    unsigned key[TK_KEYS];
    #pragma unroll
    for (int j = 0; j < TK_KEYS; ++j) {
        int i = tid + j * TK_THREADS;
        key[j] = (i < PP) ? __float_as_uint(lcm[(size_t)b * PP + i]) : 0u;
    }
    __shared__ int s_hist[8][256];           // per-wave private histograms
    __shared__ int s_vk[2];                  // {selected byte, next kk}
    __syncthreads();
    const int np = s_npb;
    int k = NEGPOS * np;
    if (k > PP - 1) k = PP - 1;

    unsigned P = 0;
    int kk = k;
    #pragma unroll
    for (int rd = 0; rd < 4; ++rd) {
        const int shift = 24 - 8 * rd;
        for (int i = tid; i < 8 * 256; i += TK_THREADS)
            ((int*)s_hist)[i] = 0;
        __syncthreads();
        const unsigned hi_mask = (rd == 0) ? 0u : (0xFFFFFFFFu << (shift + 8));
        #pragma unroll
        for (int j = 0; j < TK_KEYS; ++j) {
            int i = tid + j * TK_THREADS;
            if (i < PP && (((key[j] ^ P) & hi_mask) == 0u))
                atomicAdd(&s_hist[wv][(key[j] >> shift) & 255], 1);
        }
        __syncthreads();
        if (tid < 64) {                      // wave 0: reduce 8 copies + scan
            int h0 = 0, h1 = 0, h2 = 0, h3 = 0;
            #pragma unroll
            for (int w = 0; w < 8; ++w) {
                h0 += s_hist[w][4 * tid + 0];
                h1 += s_hist[w][4 * tid + 1];
                h2 += s_hist[w][4 * tid + 2];
                h3 += s_hist[w][4 * tid + 3];
            }
            int s3 = h3, s2 = h2 + s3, s1 = h1 + s2, s0 = h0 + s1;
            int acc = s0;
            #pragma unroll
            for (int o = 1; o < 64; o <<= 1) {
                int t = __shfl_down(acc, o);
                if (tid + o < 64) acc += t;  // inclusive suffix over lane totals
            }
            int excl = acc - s0;
            int c0 = s0 + excl, c1 = s1 + excl, c2 = s2 + excl, c3 = s3 + excl;
            unsigned long long m = __ballot(c0 >= kk);
            int L = 63 - __clzll(m);         // highest lane containing the pivot
            if (tid == L) {
                int vi, cnext;
                if (c3 >= kk)      { vi = 3; cnext = excl; }
                else if (c2 >= kk) { vi = 2; cnext = c3; }
                else if (c1 >= kk) { vi = 1; cnext = c2; }
                else               { vi = 0; cnext = c1; }
                s_vk[0] = 4 * tid + vi;
                s_vk[1] = kk - cnext;
            }
        }
        __syncthreads();
        P |= ((unsigned)s_vk[0]) << shift;
        kk = s_vk[1];
        __syncthreads();                     // s_hist reused next round
    }

    const unsigned T = P;
    float sum = 0.f;
    int cgt = 0;
    #pragma unroll
    for (int j = 0; j < TK_KEYS; ++j) {
        if (key[j] > T) { sum += __uint_as_float(key[j]); cgt++; }
    }
    for (int o = 32; o > 0; o >>= 1) {
        sum += __shfl_down(sum, o);
        cgt += __shfl_down(cgt, o);
    }
    __shared__ float s_s[8];
    __shared__ int s_c[8];
    __shared__ int s_last;
    if ((tid & 63) == 0) { s_s[wv] = sum; s_c[wv] = cgt; }
    __syncthreads();
    if (tid == 0) {
        float tot = 0.f; int ctot = 0;
        for (int w = 0; w < 8; ++w) { tot += s_s[w]; ctot += s_c[w]; }
        float neg = tot + (float)(k - ctot) * __uint_as_float(T);
        atomicAdd(&accum[0], (double)neg);
        atomicAdd(nsum, np);
        __threadfence();
        s_last = (atomicAdd(done_cnt, 1) == BB - 1) ? 1 : 0;
    }
    __syncthreads();

    if (s_last) {                            // last block: finalize
        double acc = 0.0;
        for (int i = tid; i < NBLK; i += TK_THREADS)
            acc += (double)llp_part[i];      // cross-dispatch data: plain OK
        for (int o = 32; o > 0; o >>= 1) acc += __shfl_down(acc, o);
        __shared__ double s_d[8];
        if ((tid & 63) == 0) s_d[wv] = acc;
        __syncthreads();
        if (tid == 0) {
            double llp_tot = 0.0;
            for (int w = 0; w < 8; ++w) llp_tot += s_d[w];
            double neg_tot = atomicAdd(&accum[0], 0.0);
            int N = atomicAdd(nsum, 0);
            out[0] = (float)((llp_tot + neg_tot) / (double)N);   // ALPHA = 1
        }
    }
}

extern "C" void kernel_launch(void* const* d_in, const int* in_sizes, int n_in,
                              void* d_out, int out_size, void* d_ws, size_t ws_size,
                              hipStream_t stream) {
    const float* loc_data  = (const float*)d_in[0];
    const float* conf_data = (const float*)d_in[1];
    const float* priors    = (const float*)d_in[2];
    const float* targets   = (const float*)d_in[3];

    char* ws = (char*)d_ws;
    // layout: [0,8) double accum[1]; [8,12) int nsum; [12,16) int done_cnt;
    //         [512, 512+64*16*8*8=66048) u64 g_best_part[b][t][chunk];
    //         [66048, +NBLK*4) float llp_part; [74784, +NBLK*8) int2 np_part;
    //         [92256, +BB*PP*4) float lcm
    double* accum = (double*)ws;
    int* nsum = (int*)(ws + 8);
    int* done_cnt = (int*)(ws + 12);
    unsigned long long* g_best_part = (unsigned long long*)(ws + 512);
    float* llp_part = (float*)(ws + 66048);
    int2* np_part = (int2*)(ws + 74784);
    float* lcm = (float*)(ws + 92256);

    // no memset dispatch: all partials plain-stored and fully overwritten;
    // accum/nsum/done_cnt zeroed inside k_matchA (stream-ordered).

    dim3 mg(NCHUNK, BB);
    k_matchA<<<mg, 256, 0, stream>>>(priors, targets, g_best_part,
                                     accum, nsum, done_cnt);

    k_conf_fused<<<NBLK, 256, 0, stream>>>(loc_data, conf_data, priors, targets,
                                           g_best_part, lcm, llp_part, np_part);

    k_topk<<<BB, TK_THREADS, 0, stream>>>(lcm, np_part, llp_part,
                                          accum, nsum, done_cnt, (float*)d_out);
}